// Round 2
// baseline (696.029 us; speedup 1.0000x reference)
//
#include <hip/hip_runtime.h>

// LinearAttentionRelation fused plan (round 2 = round 1 + compact workspace):
//   out2 = Wo * blockdiag(ctx_h^T) * Wq * x  => precompute Wfinal_b = Wo*Wq'_b (512x512/batch)
//   eliminates Q-proj GEMM and out-GEMM entirely.
// B=16, C=512, HEADS=8, D=64, N=4096.
// All GEMMs: C[m][nc] = sum_k A[m][k] * Bt[nc][k]  (both operands K-contiguous, bf16 MFMA 16x16x32)
// LDS "slab" layout [k4][rows][8]; global_load_lds(16B) staging (wave-uniform dest + lane*16 rule).
// Scratch budget: d_ws ~138 MB (xT, K, weights, Wfin, stats); d_out hosts ctxP/V/ctxT/WqpT (dead
// before kgemm_f32res writes y over all of d_out).

typedef __bf16 bf16_t;
typedef bf16_t bf16x8 __attribute__((ext_vector_type(8)));
typedef float f32x4 __attribute__((ext_vector_type(4)));
typedef unsigned short u16;

__device__ __forceinline__ u16 f2bf(float f) {
    unsigned u = __builtin_bit_cast(unsigned, f);
    u += 0x7FFFu + ((u >> 16) & 1u);   // RNE
    return (u16)(u >> 16);
}
__device__ __forceinline__ float bf2f(u16 h) {
    return __builtin_bit_cast(float, ((unsigned)h) << 16);
}

__device__ __forceinline__ void gload_lds16(const u16* g, u16* l) {
    __builtin_amdgcn_global_load_lds((const __attribute__((address_space(1))) void*)g,
                                     (__attribute__((address_space(3))) void*)l, 16, 0, 0);
}
__device__ __forceinline__ bf16x8 ldfrag(const u16* p) {
    return *(const bf16x8*)p;
}

// ---------------- weight cast (+ Wq transpose) ----------------
__global__ __launch_bounds__(256) void cast_weights(const float* __restrict__ Wq, const float* __restrict__ Wk,
                                                    const float* __restrict__ Wv, const float* __restrict__ Wo,
                                                    u16* __restrict__ WqT, u16* __restrict__ WkB,
                                                    u16* __restrict__ WvB, u16* __restrict__ WoB) {
    int i = blockIdx.x * 256 + threadIdx.x;      // 0..262143
    WkB[i] = f2bf(Wk[i]);
    WvB[i] = f2bf(Wv[i]);
    WoB[i] = f2bf(Wo[i]);
    int o = i >> 9, c = i & 511;
    WqT[c * 512 + o] = f2bf(Wq[i]);              // WqT[c][o]
}

// ---------------- x [b][512][4096] f32 -> xT [b][4096][512] bf16 ----------------
__global__ __launch_bounds__(256) void transpose_cast(const float* __restrict__ x, u16* __restrict__ xT) {
    __shared__ u16 tile[64][65];
    int nt = blockIdx.x, ct = blockIdx.y, b = blockIdx.z;
    const float* xb = x + ((size_t)b * 512 + ct * 64) * 4096 + nt * 64;
    int t = threadIdx.x;
#pragma unroll
    for (int i = 0; i < 16; ++i) {
        int idx = i * 256 + t;
        int cl = idx >> 6, nl = idx & 63;
        tile[cl][nl] = f2bf(xb[(size_t)cl * 4096 + nl]);
    }
    __syncthreads();
    u16* xTb = xT + ((size_t)b * 4096 + nt * 64) * 512 + ct * 64;
#pragma unroll
    for (int i = 0; i < 16; ++i) {
        int idx = i * 256 + t;
        int nl = idx >> 6, cl = idx & 63;
        xTb[(size_t)nl * 512 + cl] = tile[cl][nl];
    }
}

// ---------------- shared 128x128x512 GEMM core ----------------
__device__ __forceinline__ void gemm128_core(const u16* __restrict__ Ab, const u16* __restrict__ Btb,
                                             u16* Asl, u16* Bsl, f32x4 acc[4][4]) {
    const int t = threadIdx.x;
    const int l = t & 63, w = t >> 6;
    const int lrow = l & 15, lk = l >> 4;
    const int wm = w >> 1, wn = w & 1;
    const int r0 = t & 127, k40 = t >> 7;        // chunk q0 = t
    const int r1 = r0, k41 = k40 + 2;            // chunk q1 = t + 256
    for (int kt = 0; kt < 16; ++kt) {
        const int kb = kt * 32;
        __syncthreads();
        gload_lds16(Ab + (size_t)r0 * 512 + kb + k40 * 8, Asl + t * 8);
        gload_lds16(Ab + (size_t)r1 * 512 + kb + k41 * 8, Asl + (t + 256) * 8);
        gload_lds16(Btb + (size_t)r0 * 512 + kb + k40 * 8, Bsl + t * 8);
        gload_lds16(Btb + (size_t)r1 * 512 + kb + k41 * 8, Bsl + (t + 256) * 8);
        __syncthreads();
        bf16x8 av[4], bv[4];
#pragma unroll
        for (int fi = 0; fi < 4; ++fi)
            av[fi] = ldfrag(Asl + lk * 1024 + (wm * 64 + fi * 16 + lrow) * 8);
#pragma unroll
        for (int fj = 0; fj < 4; ++fj)
            bv[fj] = ldfrag(Bsl + lk * 1024 + (wn * 64 + fj * 16 + lrow) * 8);
#pragma unroll
        for (int fi = 0; fi < 4; ++fi)
#pragma unroll
            for (int fj = 0; fj < 4; ++fj)
                acc[fi][fj] = __builtin_amdgcn_mfma_f32_16x16x32_bf16(av[fi], bv[fj], acc[fi][fj], 0, 0, 0);
    }
}

// ---------------- GEMM -> bf16 out (used for K, V, Wfinal) ----------------
__global__ __launch_bounds__(256) void kgemm_bf16(const u16* __restrict__ A, long long sA,
                                                  const u16* __restrict__ Bt, long long sB,
                                                  u16* __restrict__ C, long long sC, int ldc, int Nt) {
    __shared__ __align__(16) u16 lds[8192];
    const int b = blockIdx.y;
    const int bm = blockIdx.x / Nt, bn = blockIdx.x % Nt;
    const u16* Ab = A + (size_t)b * sA + (size_t)bm * 128 * 512;
    const u16* Btb = Bt + (size_t)b * sB + (size_t)bn * 128 * 512;
    f32x4 acc[4][4];
#pragma unroll
    for (int i = 0; i < 4; ++i)
#pragma unroll
        for (int j = 0; j < 4; ++j) acc[i][j] = (f32x4){0.f, 0.f, 0.f, 0.f};
    gemm128_core(Ab, Btb, lds, lds + 4096, acc);
    const int t = threadIdx.x, l = t & 63, w = t >> 6;
    const int lrow = l & 15, lk = l >> 4;
    const int wm = w >> 1, wn = w & 1;
    u16* Cb = C + (size_t)b * sC;
#pragma unroll
    for (int fi = 0; fi < 4; ++fi)
#pragma unroll
        for (int fj = 0; fj < 4; ++fj)
#pragma unroll
            for (int r = 0; r < 4; ++r) {
                int m = bm * 128 + wm * 64 + fi * 16 + lk * 4 + r;
                int n = bn * 128 + wn * 64 + fj * 16 + lrow;
                Cb[(size_t)m * ldc + n] = f2bf(acc[fi][fj][r]);
            }
}

// ---------------- final GEMM + residual + BN stats (f32 out to d_out) ----------------
__global__ __launch_bounds__(256) void kgemm_f32res(const u16* __restrict__ A, long long sA,
                                                    const u16* __restrict__ Bt, long long sB,
                                                    const float* __restrict__ xres, float* __restrict__ y,
                                                    float* __restrict__ sums, float* __restrict__ sumsq, int Nt) {
    __shared__ __align__(16) u16 lds[8192];
    const int b = blockIdx.y;
    const int bm = blockIdx.x / Nt, bn = blockIdx.x % Nt;
    const u16* Ab = A + (size_t)b * sA + (size_t)bm * 128 * 512;
    const u16* Btb = Bt + (size_t)b * sB + (size_t)bn * 128 * 512;
    f32x4 acc[4][4];
#pragma unroll
    for (int i = 0; i < 4; ++i)
#pragma unroll
        for (int j = 0; j < 4; ++j) acc[i][j] = (f32x4){0.f, 0.f, 0.f, 0.f};
    gemm128_core(Ab, Btb, lds, lds + 4096, acc);
    const int t = threadIdx.x, l = t & 63, w = t >> 6;
    const int lrow = l & 15, lk = l >> 4;
    const int wm = w >> 1, wn = w & 1;
#pragma unroll
    for (int fi = 0; fi < 4; ++fi)
#pragma unroll
        for (int r = 0; r < 4; ++r) {
            int mg = bm * 128 + wm * 64 + fi * 16 + lk * 4 + r;             // channel
            size_t rowbase = (size_t)b * 2097152 + (size_t)mg * 4096 + bn * 128 + wn * 64;
            float rs = 0.f, rq = 0.f;
#pragma unroll
            for (int fj = 0; fj < 4; ++fj) {
                int nc = fj * 16 + lrow;
                float v = acc[fi][fj][r] + xres[rowbase + nc];
                y[rowbase + nc] = v;
                rs += v; rq += v * v;
            }
#pragma unroll
            for (int off = 1; off < 16; off <<= 1) {
                rs += __shfl_xor(rs, off);
                rq += __shfl_xor(rq, off);
            }
            if (lrow == 0) {
                atomicAdd(&sums[mg], rs);
                atomicAdd(&sumsq[mg], rq);
            }
        }
}

// ---------------- softmax over head-dim (in place on K [b][512][4096]) ----------------
__global__ __launch_bounds__(256) void softmax_k(u16* __restrict__ K) {
    int gid = blockIdx.x * 256 + threadIdx.x;    // 16*8*4096 = 524288
    int n = gid & 4095, bh = gid >> 12;
    u16* p = K + (size_t)bh * 64 * 4096 + n;
    float v[64];
    float m = -1e30f;
#pragma unroll
    for (int d = 0; d < 64; ++d) { v[d] = bf2f(p[(size_t)d * 4096]); m = fmaxf(m, v[d]); }
    float s = 0.f;
#pragma unroll
    for (int d = 0; d < 64; ++d) { v[d] = __expf(v[d] - m); s += v[d]; }
    float inv = 1.0f / s;
#pragma unroll
    for (int d = 0; d < 64; ++d) p[(size_t)d * 4096] = f2bf(v[d] * inv);
}

// ---------------- ctx partials: per (b,h,ks) 64x64 over K-range 512 ----------------
__global__ __launch_bounds__(256) void ctx_partial(const u16* __restrict__ Ksm, const u16* __restrict__ V,
                                                   float* __restrict__ P) {
    __shared__ __align__(16) u16 lds[4096];
    const int bh = blockIdx.x >> 3, ks = blockIdx.x & 7;
    const u16* Ab = Ksm + (size_t)bh * 64 * 4096;
    const u16* Btb = V + (size_t)bh * 64 * 4096;
    u16* Asl = lds; u16* Bsl = lds + 2048;
    const int t = threadIdx.x, l = t & 63, w = t >> 6;
    const int lrow = l & 15, lk = l >> 4;
    const int wm = w >> 1, wn = w & 1;
    const int row = t & 63, k4 = t >> 6;
    f32x4 acc[2][2];
#pragma unroll
    for (int i = 0; i < 2; ++i)
#pragma unroll
        for (int j = 0; j < 2; ++j) acc[i][j] = (f32x4){0.f, 0.f, 0.f, 0.f};
    for (int kt = 0; kt < 16; ++kt) {
        int kb = ks * 512 + kt * 32;
        __syncthreads();
        gload_lds16(Ab + (size_t)row * 4096 + kb + k4 * 8, Asl + t * 8);
        gload_lds16(Btb + (size_t)row * 4096 + kb + k4 * 8, Bsl + t * 8);
        __syncthreads();
        bf16x8 av[2], bv[2];
#pragma unroll
        for (int fi = 0; fi < 2; ++fi)
            av[fi] = ldfrag(Asl + lk * 512 + (wm * 32 + fi * 16 + lrow) * 8);
#pragma unroll
        for (int fj = 0; fj < 2; ++fj)
            bv[fj] = ldfrag(Bsl + lk * 512 + (wn * 32 + fj * 16 + lrow) * 8);
#pragma unroll
        for (int fi = 0; fi < 2; ++fi)
#pragma unroll
            for (int fj = 0; fj < 2; ++fj)
                acc[fi][fj] = __builtin_amdgcn_mfma_f32_16x16x32_bf16(av[fi], bv[fj], acc[fi][fj], 0, 0, 0);
    }
    float* Pb = P + (size_t)blockIdx.x * 4096;
#pragma unroll
    for (int fi = 0; fi < 2; ++fi)
#pragma unroll
        for (int fj = 0; fj < 2; ++fj)
#pragma unroll
            for (int r = 0; r < 4; ++r) {
                int m = wm * 32 + fi * 16 + lk * 4 + r;
                int e = wn * 32 + fj * 16 + lrow;
                Pb[m * 64 + e] = acc[fi][fj][r];
            }
}

// ---------------- reduce 8 partials -> ctxT[bh][e][d] bf16 ----------------
__global__ __launch_bounds__(256) void ctx_reduce(const float* __restrict__ P, u16* __restrict__ ctxT) {
    int gid = blockIdx.x * 256 + threadIdx.x;    // 524288
    int d = gid & 63, e = (gid >> 6) & 63, bh = gid >> 12;
    const float* p = P + (size_t)bh * 8 * 4096 + d * 64 + e;
    float s = 0.f;
#pragma unroll
    for (int ks = 0; ks < 8; ++ks) s += p[(size_t)ks * 4096];
    ctxT[(size_t)bh * 4096 + e * 64 + d] = f2bf(s);
}

// ---------------- Wq'^T[b][c][h*64+e] = sum_d ctxT[bh][e][d] * WqT[c][h*64+d] ----------------
__global__ __launch_bounds__(256) void kgemm_wqp(const u16* __restrict__ ctxT, const u16* __restrict__ WqT,
                                                 u16* __restrict__ WqpT) {
    __shared__ __align__(16) u16 lds[4096 + 8192];
    const int nq = blockIdx.x, bh = blockIdx.y;
    const int b = bh >> 3, h = bh & 7;
    const u16* Ab = ctxT + (size_t)bh * 4096;                       // [e][d] lda=64
    const u16* Btb = WqT + (size_t)nq * 128 * 512 + h * 64;         // rows c, ldb=512
    u16* Asl = lds; u16* Bsl = lds + 4096;
    const int t = threadIdx.x, l = t & 63, w = t >> 6;
    const int lrow = l & 15, lk = l >> 4;
    {
        int q = t;
        gload_lds16(Ab + (size_t)(q & 63) * 64 + (q >> 6) * 8, Asl + q * 8);
        q = t + 256;
        gload_lds16(Ab + (size_t)(q & 63) * 64 + (q >> 6) * 8, Asl + q * 8);
    }
#pragma unroll
    for (int i = 0; i < 4; ++i) {
        int q = t + i * 256;
        gload_lds16(Btb + (size_t)(q & 127) * 512 + (q >> 7) * 8, Bsl + q * 8);
    }
    __syncthreads();
    f32x4 acc[4][2];
#pragma unroll
    for (int i = 0; i < 4; ++i)
#pragma unroll
        for (int j = 0; j < 2; ++j) acc[i][j] = (f32x4){0.f, 0.f, 0.f, 0.f};
#pragma unroll
    for (int ksv = 0; ksv < 2; ++ksv) {
        bf16x8 av[4], bv[2];
#pragma unroll
        for (int fi = 0; fi < 4; ++fi)
            av[fi] = ldfrag(Asl + (ksv * 4 + lk) * 512 + (fi * 16 + lrow) * 8);
#pragma unroll
        for (int fj = 0; fj < 2; ++fj)
            bv[fj] = ldfrag(Bsl + (ksv * 4 + lk) * 1024 + (w * 32 + fj * 16 + lrow) * 8);
#pragma unroll
        for (int fi = 0; fi < 4; ++fi)
#pragma unroll
            for (int fj = 0; fj < 2; ++fj)
                acc[fi][fj] = __builtin_amdgcn_mfma_f32_16x16x32_bf16(av[fi], bv[fj], acc[fi][fj], 0, 0, 0);
    }
    u16* Ob = WqpT + (size_t)b * 262144 + h * 64;
#pragma unroll
    for (int fi = 0; fi < 4; ++fi)
#pragma unroll
        for (int fj = 0; fj < 2; ++fj)
#pragma unroll
            for (int r = 0; r < 4; ++r) {
                int e = fi * 16 + lk * 4 + r;
                int c = nq * 128 + w * 32 + fj * 16 + lrow;
                Ob[(size_t)c * 512 + e] = f2bf(acc[fi][fj][r]);
            }
}

// ---------------- BN finalize + normalize ----------------
__global__ void bn_finalize(const float* __restrict__ sums, const float* __restrict__ sumsq,
                            const float* __restrict__ gamma, const float* __restrict__ beta,
                            float* __restrict__ scale, float* __restrict__ shift) {
    int c = threadIdx.x;                 // block of 512
    float inv = 1.0f / 65536.0f;
    float mean = sums[c] * inv;
    float var = sumsq[c] * inv - mean * mean;
    float rstd = rsqrtf(var + 1e-5f);
    float sc = rstd * gamma[c];
    scale[c] = sc;
    shift[c] = beta[c] - mean * sc;
}

__global__ __launch_bounds__(256) void bn_norm(float* __restrict__ y, const float* __restrict__ scale,
                                               const float* __restrict__ shift) {
    int i4 = blockIdx.x * 256 + threadIdx.x;   // 8388608 float4s
    float4* Y = (float4*)y;
    float4 v = Y[i4];
    int c = (i4 >> 10) & 511;
    float sc = scale[c], sh = shift[c];
    v.x = v.x * sc + sh; v.y = v.y * sc + sh; v.z = v.z * sc + sh; v.w = v.w * sc + sh;
    Y[i4] = v;
}

extern "C" void kernel_launch(void* const* d_in, const int* in_sizes, int n_in,
                              void* d_out, int out_size, void* d_ws, size_t ws_size,
                              hipStream_t stream) {
    const float* x     = (const float*)d_in[0];
    const float* Wq    = (const float*)d_in[1];
    const float* Wk    = (const float*)d_in[2];
    const float* Wv    = (const float*)d_in[3];
    const float* Wo    = (const float*)d_in[4];
    const float* gamma = (const float*)d_in[5];
    const float* beta  = (const float*)d_in[6];

    // ---- d_ws layout (~138 MiB): xT | K | WqT,WkB,WvB,WoB | Wfinal | stats ----
    char* w = (char*)d_ws;
    u16* xT   = (u16*)(w);                                     //  64 MiB
    u16* Kbuf = (u16*)(w + 67108864ull);                       //  64 MiB
    u16* WqT  = (u16*)(w + 134217728ull);                      // 512 KiB
    u16* WkB  = WqT + 262144;
    u16* WvB  = WkB + 262144;
    u16* WoB  = WvB + 262144;
    u16* Wfin = WoB + 262144;                                  // 16*262144 u16 = 8 MiB
    float* sums  = (float*)(w + 134217728ull + 2097152ull + 8388608ull);
    float* sumsq = sums + 512;
    float* scale = sums + 1024;
    float* shift = sums + 1536;

    // ---- d_out doubles as scratch (all dead before kgemm_f32res writes y) ----
    char* ob = (char*)d_out;
    float* ctxP = (float*)ob;                                  // 16 MiB  @0
    u16* Vbuf   = (u16*)(ob + 16777216ull);                    // 64 MiB  @16M
    u16* ctxT   = (u16*)(ob + 83886080ull);                    //  1 MiB  @80M
    u16* WqpT   = (u16*)(ob + 84934656ull);                    //  8 MiB  @81M
    float* y    = (float*)d_out;

    hipMemsetAsync(sums, 0, 4096, stream);
    cast_weights<<<1024, 256, 0, stream>>>(Wq, Wk, Wv, Wo, WqT, WkB, WvB, WoB);
    transpose_cast<<<dim3(64, 8, 16), 256, 0, stream>>>(x, xT);
    kgemm_bf16<<<dim3(128, 16), 256, 0, stream>>>(WkB, 0, xT, 2097152, Kbuf, 2097152, 4096, 32);
    kgemm_bf16<<<dim3(128, 16), 256, 0, stream>>>(WvB, 0, xT, 2097152, Vbuf, 2097152, 4096, 32);
    softmax_k<<<2048, 256, 0, stream>>>(Kbuf);
    ctx_partial<<<1024, 256, 0, stream>>>(Kbuf, Vbuf, ctxP);
    ctx_reduce<<<2048, 256, 0, stream>>>(ctxP, ctxT);
    kgemm_wqp<<<dim3(4, 128), 256, 0, stream>>>(ctxT, WqT, WqpT);
    kgemm_bf16<<<dim3(16, 16), 256, 0, stream>>>(WoB, 0, WqpT, 262144, Wfin, 262144, 512, 4);
    kgemm_f32res<<<dim3(128, 16), 256, 0, stream>>>(Wfin, 262144, xT, 2097152, x, y, sums, sumsq, 32);
    bn_finalize<<<1, 512, 0, stream>>>(sums, sumsq, gamma, beta, scale, shift);
    bn_norm<<<32768, 256, 0, stream>>>(y, scale, shift);
}

// Round 3
// 675.918 us; speedup vs baseline: 1.0298x; 1.0298x over previous
//
#include <hip/hip_runtime.h>

// LinearAttentionRelation fused plan (round 3):
//   out2 = Wo * blockdiag(ctx_h^T) * Wq * x  => precompute Wfinal_b = Wo*Wq'_b (512x512/batch)
// Round-3 changes vs round-2 (which passed @696us, absmax 0.031):
//   1. All GEMM K-loops use 2-phase LDS double-buffer (T3-minimum: STAGE(next) at top,
//      one __syncthreads()=vmcnt(0)+barrier per iter) -> overlap staging with ds_read+MFMA.
//   2. K and V projections fused into ONE stacked GEMM (A=[Wk;Wv], M=1024).
//   3. y intermediate stored as bf16 (reuses dead Kbuf region) -> 64MB instead of 256MB,
//      bn_norm reads bf16 writes f32 d_out. Costs ~+0.01 absmax, saves ~250MB traffic.
// B=16, C=512, HEADS=8, D=64, N=4096.
// GEMM convention: C[m][n] = sum_k A[m][k]*Bt[n][k] (both K-contiguous, mfma 16x16x32 bf16).
// LDS slab layout [k4][rows][8] u16; global_load_lds 16B staging (wave-uniform base + lane*16).

typedef __bf16 bf16_t;
typedef bf16_t bf16x8 __attribute__((ext_vector_type(8)));
typedef float f32x4 __attribute__((ext_vector_type(4)));
typedef unsigned short u16;

__device__ __forceinline__ u16 f2bf(float f) {
    unsigned u = __builtin_bit_cast(unsigned, f);
    u += 0x7FFFu + ((u >> 16) & 1u);   // RNE
    return (u16)(u >> 16);
}
__device__ __forceinline__ float bf2f(u16 h) {
    return __builtin_bit_cast(float, ((unsigned)h) << 16);
}

__device__ __forceinline__ void gload_lds16(const u16* g, u16* l) {
    __builtin_amdgcn_global_load_lds((const __attribute__((address_space(1))) void*)g,
                                     (__attribute__((address_space(3))) void*)l, 16, 0, 0);
}
__device__ __forceinline__ bf16x8 ldfrag(const u16* p) {
    return *(const bf16x8*)p;
}

// ---------------- weight cast (+ Wq transpose) ----------------
__global__ __launch_bounds__(256) void cast_weights(const float* __restrict__ Wq, const float* __restrict__ Wk,
                                                    const float* __restrict__ Wv, const float* __restrict__ Wo,
                                                    u16* __restrict__ WqT, u16* __restrict__ WkB,
                                                    u16* __restrict__ WvB, u16* __restrict__ WoB) {
    int i = blockIdx.x * 256 + threadIdx.x;      // 0..262143
    WkB[i] = f2bf(Wk[i]);
    WvB[i] = f2bf(Wv[i]);
    WoB[i] = f2bf(Wo[i]);
    int o = i >> 9, c = i & 511;
    WqT[c * 512 + o] = f2bf(Wq[i]);              // WqT[c][o]
}

// ---------------- x [b][512][4096] f32 -> xT [b][4096][512] bf16 ----------------
__global__ __launch_bounds__(256) void transpose_cast(const float* __restrict__ x, u16* __restrict__ xT) {
    __shared__ u16 tile[64][65];
    int nt = blockIdx.x, ct = blockIdx.y, b = blockIdx.z;
    const float* xb = x + ((size_t)b * 512 + ct * 64) * 4096 + nt * 64;
    int t = threadIdx.x;
#pragma unroll
    for (int i = 0; i < 16; ++i) {
        int idx = i * 256 + t;
        int cl = idx >> 6, nl = idx & 63;
        tile[cl][nl] = f2bf(xb[(size_t)cl * 4096 + nl]);
    }
    __syncthreads();
    u16* xTb = xT + ((size_t)b * 4096 + nt * 64) * 512 + ct * 64;
#pragma unroll
    for (int i = 0; i < 16; ++i) {
        int idx = i * 256 + t;
        int nl = idx >> 6, cl = idx & 63;
        xTb[(size_t)nl * 512 + cl] = tile[cl][nl];
    }
}

// ---------------- 128x128x512 GEMM core, 2-phase LDS double-buffer ----------------
// lds: 16384 u16 = 32KB. buf layout: A0@0, B0@4096, A1@8192, B1@12288 (u16 units).
__device__ __forceinline__ void gemm128_dbuf(const u16* __restrict__ Ab, const u16* __restrict__ Btb,
                                             u16* lds, f32x4 acc[4][4]) {
    const int t = threadIdx.x;
    const int l = t & 63, w = t >> 6;
    const int lrow = l & 15, lk = l >> 4;
    const int wm = w >> 1, wn = w & 1;
    const int r0 = t & 127, k40 = t >> 7;
    // prologue: stage tile 0 into buf0
    gload_lds16(Ab + (size_t)r0 * 512 + k40 * 8, lds + t * 8);
    gload_lds16(Ab + (size_t)r0 * 512 + (k40 + 2) * 8, lds + (t + 256) * 8);
    gload_lds16(Btb + (size_t)r0 * 512 + k40 * 8, lds + 4096 + t * 8);
    gload_lds16(Btb + (size_t)r0 * 512 + (k40 + 2) * 8, lds + 4096 + (t + 256) * 8);
    __syncthreads();
    for (int kt = 0; kt < 16; ++kt) {
        const int cur = (kt & 1) << 13;          // 0 / 8192
        const int nxt = cur ^ 8192;
        if (kt < 15) {                           // issue next-tile loads FIRST (in flight during compute)
            const int kb = (kt + 1) * 32;
            gload_lds16(Ab + (size_t)r0 * 512 + kb + k40 * 8, lds + nxt + t * 8);
            gload_lds16(Ab + (size_t)r0 * 512 + kb + (k40 + 2) * 8, lds + nxt + (t + 256) * 8);
            gload_lds16(Btb + (size_t)r0 * 512 + kb + k40 * 8, lds + nxt + 4096 + t * 8);
            gload_lds16(Btb + (size_t)r0 * 512 + kb + (k40 + 2) * 8, lds + nxt + 4096 + (t + 256) * 8);
        }
        bf16x8 av[4], bv[4];
#pragma unroll
        for (int fi = 0; fi < 4; ++fi)
            av[fi] = ldfrag(lds + cur + lk * 1024 + (wm * 64 + fi * 16 + lrow) * 8);
#pragma unroll
        for (int fj = 0; fj < 4; ++fj)
            bv[fj] = ldfrag(lds + cur + 4096 + lk * 1024 + (wn * 64 + fj * 16 + lrow) * 8);
#pragma unroll
        for (int fi = 0; fi < 4; ++fi)
#pragma unroll
            for (int fj = 0; fj < 4; ++fj)
                acc[fi][fj] = __builtin_amdgcn_mfma_f32_16x16x32_bf16(av[fi], bv[fj], acc[fi][fj], 0, 0, 0);
        __syncthreads();                         // vmcnt(0)+lgkmcnt(0)+barrier: next tile staged, cur reads done
    }
}

// ---------------- stacked [K;V] projection GEMM (M=1024) ----------------
__global__ __launch_bounds__(256) void kgemm_kv(const u16* __restrict__ Wkv, const u16* __restrict__ xT,
                                                u16* __restrict__ K, u16* __restrict__ V) {
    __shared__ __align__(16) u16 lds[16384];
    const int b = blockIdx.y;
    const int bm = blockIdx.x >> 5, bn = blockIdx.x & 31;
    const u16* Ab = Wkv + (size_t)bm * 128 * 512;
    const u16* Btb = xT + (size_t)b * 2097152 + (size_t)bn * 128 * 512;
    f32x4 acc[4][4];
#pragma unroll
    for (int i = 0; i < 4; ++i)
#pragma unroll
        for (int j = 0; j < 4; ++j) acc[i][j] = (f32x4){0.f, 0.f, 0.f, 0.f};
    gemm128_dbuf(Ab, Btb, lds, acc);
    const int t = threadIdx.x, l = t & 63, w = t >> 6;
    const int lrow = l & 15, lk = l >> 4;
    const int wm = w >> 1, wn = w & 1;
    u16* Cb = (bm < 4) ? (K + (size_t)b * 2097152 + (size_t)bm * 128 * 4096)
                       : (V + (size_t)b * 2097152 + (size_t)(bm - 4) * 128 * 4096);
#pragma unroll
    for (int fi = 0; fi < 4; ++fi)
#pragma unroll
        for (int fj = 0; fj < 4; ++fj)
#pragma unroll
            for (int r = 0; r < 4; ++r) {
                int m = wm * 64 + fi * 16 + lk * 4 + r;
                int n = bn * 128 + wn * 64 + fj * 16 + lrow;
                Cb[(size_t)m * 4096 + n] = f2bf(acc[fi][fj][r]);
            }
}

// ---------------- generic GEMM -> bf16 out (used for Wfinal) ----------------
__global__ __launch_bounds__(256) void kgemm_bf16(const u16* __restrict__ A, long long sA,
                                                  const u16* __restrict__ Bt, long long sB,
                                                  u16* __restrict__ C, long long sC, int ldc, int Nt) {
    __shared__ __align__(16) u16 lds[16384];
    const int b = blockIdx.y;
    const int bm = blockIdx.x / Nt, bn = blockIdx.x % Nt;
    const u16* Ab = A + (size_t)b * sA + (size_t)bm * 128 * 512;
    const u16* Btb = Bt + (size_t)b * sB + (size_t)bn * 128 * 512;
    f32x4 acc[4][4];
#pragma unroll
    for (int i = 0; i < 4; ++i)
#pragma unroll
        for (int j = 0; j < 4; ++j) acc[i][j] = (f32x4){0.f, 0.f, 0.f, 0.f};
    gemm128_dbuf(Ab, Btb, lds, acc);
    const int t = threadIdx.x, l = t & 63, w = t >> 6;
    const int lrow = l & 15, lk = l >> 4;
    const int wm = w >> 1, wn = w & 1;
    u16* Cb = C + (size_t)b * sC;
#pragma unroll
    for (int fi = 0; fi < 4; ++fi)
#pragma unroll
        for (int fj = 0; fj < 4; ++fj)
#pragma unroll
            for (int r = 0; r < 4; ++r) {
                int m = bm * 128 + wm * 64 + fi * 16 + lk * 4 + r;
                int n = bn * 128 + wn * 64 + fj * 16 + lrow;
                Cb[(size_t)m * ldc + n] = f2bf(acc[fi][fj][r]);
            }
}

// ---------------- final GEMM + residual + BN stats, bf16 y out ----------------
__global__ __launch_bounds__(256) void kgemm_f32res(const u16* __restrict__ Wfin, const u16* __restrict__ xT,
                                                    const float* __restrict__ xres, u16* __restrict__ yb,
                                                    float* __restrict__ sums, float* __restrict__ sumsq) {
    __shared__ __align__(16) u16 lds[16384];
    const int b = blockIdx.y;
    const int bm = blockIdx.x >> 5, bn = blockIdx.x & 31;
    const u16* Ab = Wfin + (size_t)b * 262144 + (size_t)bm * 128 * 512;
    const u16* Btb = xT + (size_t)b * 2097152 + (size_t)bn * 128 * 512;
    f32x4 acc[4][4];
#pragma unroll
    for (int i = 0; i < 4; ++i)
#pragma unroll
        for (int j = 0; j < 4; ++j) acc[i][j] = (f32x4){0.f, 0.f, 0.f, 0.f};
    gemm128_dbuf(Ab, Btb, lds, acc);
    const int t = threadIdx.x, l = t & 63, w = t >> 6;
    const int lrow = l & 15, lk = l >> 4;
    const int wm = w >> 1, wn = w & 1;
#pragma unroll
    for (int fi = 0; fi < 4; ++fi)
#pragma unroll
        for (int r = 0; r < 4; ++r) {
            int mg = bm * 128 + wm * 64 + fi * 16 + lk * 4 + r;             // channel
            size_t rowbase = (size_t)b * 2097152 + (size_t)mg * 4096 + bn * 128 + wn * 64;
            float rs = 0.f, rq = 0.f;
#pragma unroll
            for (int fj = 0; fj < 4; ++fj) {
                int nc = fj * 16 + lrow;
                float v = acc[fi][fj][r] + xres[rowbase + nc];
                yb[rowbase + nc] = f2bf(v);
                rs += v; rq += v * v;
            }
#pragma unroll
            for (int off = 1; off < 16; off <<= 1) {
                rs += __shfl_xor(rs, off);
                rq += __shfl_xor(rq, off);
            }
            if (lrow == 0) {
                atomicAdd(&sums[mg], rs);
                atomicAdd(&sumsq[mg], rq);
            }
        }
}

// ---------------- softmax over head-dim (in place on K [b][512][4096]) ----------------
__global__ __launch_bounds__(256) void softmax_k(u16* __restrict__ K) {
    int gid = blockIdx.x * 256 + threadIdx.x;    // 16*8*4096 = 524288
    int n = gid & 4095, bh = gid >> 12;
    u16* p = K + (size_t)bh * 64 * 4096 + n;
    float v[64];
    float m = -1e30f;
#pragma unroll
    for (int d = 0; d < 64; ++d) { v[d] = bf2f(p[(size_t)d * 4096]); m = fmaxf(m, v[d]); }
    float s = 0.f;
#pragma unroll
    for (int d = 0; d < 64; ++d) { v[d] = __expf(v[d] - m); s += v[d]; }
    float inv = 1.0f / s;
#pragma unroll
    for (int d = 0; d < 64; ++d) p[(size_t)d * 4096] = f2bf(v[d] * inv);
}

// ---------------- ctx partials: per (b,h,ks) 64x64 over K-range 512, dbuf ----------------
__global__ __launch_bounds__(256) void ctx_partial(const u16* __restrict__ Ksm, const u16* __restrict__ V,
                                                   float* __restrict__ P) {
    __shared__ __align__(16) u16 lds[8192];      // A0@0,B0@2048,A1@4096,B1@6144
    const int bh = blockIdx.x >> 3, ks = blockIdx.x & 7;
    const u16* Ab = Ksm + (size_t)bh * 262144;
    const u16* Btb = V + (size_t)bh * 262144;
    const int t = threadIdx.x, l = t & 63, w = t >> 6;
    const int lrow = l & 15, lk = l >> 4;
    const int wm = w >> 1, wn = w & 1;
    const int row = t & 63, k4 = t >> 6;
    f32x4 acc[2][2];
#pragma unroll
    for (int i = 0; i < 2; ++i)
#pragma unroll
        for (int j = 0; j < 2; ++j) acc[i][j] = (f32x4){0.f, 0.f, 0.f, 0.f};
    gload_lds16(Ab + (size_t)row * 4096 + ks * 512 + k4 * 8, lds + t * 8);
    gload_lds16(Btb + (size_t)row * 4096 + ks * 512 + k4 * 8, lds + 2048 + t * 8);
    __syncthreads();
    for (int kt = 0; kt < 16; ++kt) {
        const int cur = (kt & 1) << 12;          // 0 / 4096
        const int nxt = cur ^ 4096;
        if (kt < 15) {
            const int kb = ks * 512 + (kt + 1) * 32;
            gload_lds16(Ab + (size_t)row * 4096 + kb + k4 * 8, lds + nxt + t * 8);
            gload_lds16(Btb + (size_t)row * 4096 + kb + k4 * 8, lds + nxt + 2048 + t * 8);
        }
        bf16x8 av[2], bv[2];
#pragma unroll
        for (int fi = 0; fi < 2; ++fi)
            av[fi] = ldfrag(lds + cur + lk * 512 + (wm * 32 + fi * 16 + lrow) * 8);
#pragma unroll
        for (int fj = 0; fj < 2; ++fj)
            bv[fj] = ldfrag(lds + cur + 2048 + lk * 512 + (wn * 32 + fj * 16 + lrow) * 8);
#pragma unroll
        for (int fi = 0; fi < 2; ++fi)
#pragma unroll
            for (int fj = 0; fj < 2; ++fj)
                acc[fi][fj] = __builtin_amdgcn_mfma_f32_16x16x32_bf16(av[fi], bv[fj], acc[fi][fj], 0, 0, 0);
        __syncthreads();
    }
    float* Pb = P + (size_t)blockIdx.x * 4096;
#pragma unroll
    for (int fi = 0; fi < 2; ++fi)
#pragma unroll
        for (int fj = 0; fj < 2; ++fj)
#pragma unroll
            for (int r = 0; r < 4; ++r) {
                int m = wm * 32 + fi * 16 + lk * 4 + r;
                int e = wn * 32 + fj * 16 + lrow;
                Pb[m * 64 + e] = acc[fi][fj][r];
            }
}

// ---------------- reduce 8 partials -> ctxT[bh][e][d] bf16 ----------------
__global__ __launch_bounds__(256) void ctx_reduce(const float* __restrict__ P, u16* __restrict__ ctxT) {
    int gid = blockIdx.x * 256 + threadIdx.x;    // 524288
    int d = gid & 63, e = (gid >> 6) & 63, bh = gid >> 12;
    const float* p = P + (size_t)bh * 8 * 4096 + d * 64 + e;
    float s = 0.f;
#pragma unroll
    for (int ks = 0; ks < 8; ++ks) s += p[(size_t)ks * 4096];
    ctxT[(size_t)bh * 4096 + e * 64 + d] = f2bf(s);
}

// ---------------- Wq'^T[b][c][h*64+e] = sum_d ctxT[bh][e][d] * WqT[c][h*64+d] ----------------
__global__ __launch_bounds__(256) void kgemm_wqp(const u16* __restrict__ ctxT, const u16* __restrict__ WqT,
                                                 u16* __restrict__ WqpT) {
    __shared__ __align__(16) u16 lds[4096 + 8192];
    const int nq = blockIdx.x, bh = blockIdx.y;
    const int b = bh >> 3, h = bh & 7;
    const u16* Ab = ctxT + (size_t)bh * 4096;                       // [e][d] lda=64
    const u16* Btb = WqT + (size_t)nq * 128 * 512 + h * 64;         // rows c, ldb=512
    u16* Asl = lds; u16* Bsl = lds + 4096;
    const int t = threadIdx.x, l = t & 63, w = t >> 6;
    const int lrow = l & 15, lk = l >> 4;
    {
        int q = t;
        gload_lds16(Ab + (size_t)(q & 63) * 64 + (q >> 6) * 8, Asl + q * 8);
        q = t + 256;
        gload_lds16(Ab + (size_t)(q & 63) * 64 + (q >> 6) * 8, Asl + q * 8);
    }
#pragma unroll
    for (int i = 0; i < 4; ++i) {
        int q = t + i * 256;
        gload_lds16(Btb + (size_t)(q & 127) * 512 + (q >> 7) * 8, Bsl + q * 8);
    }
    __syncthreads();
    f32x4 acc[4][2];
#pragma unroll
    for (int i = 0; i < 4; ++i)
#pragma unroll
        for (int j = 0; j < 2; ++j) acc[i][j] = (f32x4){0.f, 0.f, 0.f, 0.f};
#pragma unroll
    for (int ksv = 0; ksv < 2; ++ksv) {
        bf16x8 av[4], bv[2];
#pragma unroll
        for (int fi = 0; fi < 4; ++fi)
            av[fi] = ldfrag(Asl + (ksv * 4 + lk) * 512 + (fi * 16 + lrow) * 8);
#pragma unroll
        for (int fj = 0; fj < 2; ++fj)
            bv[fj] = ldfrag(Bsl + (ksv * 4 + lk) * 1024 + (w * 32 + fj * 16 + lrow) * 8);
#pragma unroll
        for (int fi = 0; fi < 4; ++fi)
#pragma unroll
            for (int fj = 0; fj < 2; ++fj)
                acc[fi][fj] = __builtin_amdgcn_mfma_f32_16x16x32_bf16(av[fi], bv[fj], acc[fi][fj], 0, 0, 0);
    }
    u16* Ob = WqpT + (size_t)b * 262144 + h * 64;
#pragma unroll
    for (int fi = 0; fi < 4; ++fi)
#pragma unroll
        for (int fj = 0; fj < 2; ++fj)
#pragma unroll
            for (int r = 0; r < 4; ++r) {
                int e = fi * 16 + lk * 4 + r;
                int c = nq * 128 + w * 32 + fj * 16 + lrow;
                Ob[(size_t)c * 512 + e] = f2bf(acc[fi][fj][r]);
            }
}

// ---------------- BN finalize + normalize (bf16 y -> f32 out) ----------------
__global__ void bn_finalize(const float* __restrict__ sums, const float* __restrict__ sumsq,
                            const float* __restrict__ gamma, const float* __restrict__ beta,
                            float* __restrict__ scale, float* __restrict__ shift) {
    int c = threadIdx.x;                 // block of 512
    float inv = 1.0f / 65536.0f;
    float mean = sums[c] * inv;
    float var = sumsq[c] * inv - mean * mean;
    float rstd = rsqrtf(var + 1e-5f);
    float sc = rstd * gamma[c];
    scale[c] = sc;
    shift[c] = beta[c] - mean * sc;
}

__global__ __launch_bounds__(256) void bn_norm(const u16* __restrict__ yb, const float* __restrict__ scale,
                                               const float* __restrict__ shift, float* __restrict__ out) {
    int i8 = blockIdx.x * 256 + threadIdx.x;     // 4194304 groups of 8 bf16
    uint4 raw = ((const uint4*)yb)[i8];
    int c = (i8 >> 9) & 511;                     // 8 elems/thread, 4096 n per c
    float sc = scale[c], sh = shift[c];
    float4 o0, o1;
    o0.x = bf2f((u16)(raw.x & 0xffff)) * sc + sh;  o0.y = bf2f((u16)(raw.x >> 16)) * sc + sh;
    o0.z = bf2f((u16)(raw.y & 0xffff)) * sc + sh;  o0.w = bf2f((u16)(raw.y >> 16)) * sc + sh;
    o1.x = bf2f((u16)(raw.z & 0xffff)) * sc + sh;  o1.y = bf2f((u16)(raw.z >> 16)) * sc + sh;
    o1.z = bf2f((u16)(raw.w & 0xffff)) * sc + sh;  o1.w = bf2f((u16)(raw.w >> 16)) * sc + sh;
    float4* O = (float4*)out;
    O[(size_t)i8 * 2] = o0;
    O[(size_t)i8 * 2 + 1] = o1;
}

extern "C" void kernel_launch(void* const* d_in, const int* in_sizes, int n_in,
                              void* d_out, int out_size, void* d_ws, size_t ws_size,
                              hipStream_t stream) {
    const float* x     = (const float*)d_in[0];
    const float* Wq    = (const float*)d_in[1];
    const float* Wk    = (const float*)d_in[2];
    const float* Wv    = (const float*)d_in[3];
    const float* Wo    = (const float*)d_in[4];
    const float* gamma = (const float*)d_in[5];
    const float* beta  = (const float*)d_in[6];

    // ---- d_ws layout (~138 MiB, same budget round-2 proved): xT | Kbuf(->ybuf) | weights | Wfin | stats
    char* w = (char*)d_ws;
    u16* xT   = (u16*)(w);                                     //  64 MiB
    u16* Kbuf = (u16*)(w + 67108864ull);                       //  64 MiB (reused as ybuf after ctx)
    u16* WqT  = (u16*)(w + 134217728ull);                      // 512 KiB
    u16* WkB  = WqT + 262144;                                  // [Wk;Wv] stacked (adjacent!)
    u16* WvB  = WkB + 262144;
    u16* WoB  = WvB + 262144;
    u16* Wfin = WoB + 262144;                                  // 8 MiB
    float* sums  = (float*)(w + 134217728ull + 2097152ull + 8388608ull);
    float* sumsq = sums + 512;
    float* scale = sums + 1024;
    float* shift = sums + 1536;
    u16* ybuf = Kbuf;                                          // Kbuf dead after ctx_partial

    // ---- d_out doubles as scratch (all dead before bn_norm overwrites d_out) ----
    char* ob = (char*)d_out;
    float* ctxP = (float*)ob;                                  // 16 MiB  @0
    u16* Vbuf   = (u16*)(ob + 16777216ull);                    // 64 MiB  @16M
    u16* ctxT   = (u16*)(ob + 83886080ull);                    //  1 MiB  @80M
    u16* WqpT   = (u16*)(ob + 84934656ull);                    //  8 MiB  @81M
    float* out  = (float*)d_out;

    hipMemsetAsync(sums, 0, 4096, stream);
    cast_weights<<<1024, 256, 0, stream>>>(Wq, Wk, Wv, Wo, WqT, WkB, WvB, WoB);
    transpose_cast<<<dim3(64, 8, 16), 256, 0, stream>>>(x, xT);
    kgemm_kv<<<dim3(256, 16), 256, 0, stream>>>(WkB, xT, Kbuf, Vbuf);
    softmax_k<<<2048, 256, 0, stream>>>(Kbuf);
    ctx_partial<<<1024, 256, 0, stream>>>(Kbuf, Vbuf, ctxP);
    ctx_reduce<<<2048, 256, 0, stream>>>(ctxP, ctxT);
    kgemm_wqp<<<dim3(4, 128), 256, 0, stream>>>(ctxT, WqT, WqpT);
    kgemm_bf16<<<dim3(16, 16), 256, 0, stream>>>(WoB, 0, WqpT, 262144, Wfin, 262144, 512, 4);
    kgemm_f32res<<<dim3(128, 16), 256, 0, stream>>>(Wfin, xT, x, ybuf, sums, sumsq);
    bn_finalize<<<1, 512, 0, stream>>>(sums, sumsq, gamma, beta, scale, shift);
    bn_norm<<<16384, 256, 0, stream>>>(ybuf, scale, shift, out);
}

// Round 4
// 653.189 us; speedup vs baseline: 1.0656x; 1.0348x over previous
//
#include <hip/hip_runtime.h>

// LinearAttentionRelation fused plan (round 4):
//   out2 = Wo * blockdiag(ctx_h^T) * Wq * x  => precompute Wfinal_b = Wo*Wq'_b (512x512/batch)
// Round-4 change vs round-3 (675us, absmax 0.031):
//   T3+T4 done RIGHT: ring-of-3 LDS buffers, counted s_waitcnt vmcnt(N) (never 0 mid-loop),
//   raw s_barrier (no __syncthreads vmcnt(0) drain). Round-3's dbuf+__syncthreads was a no-op
//   (174us both rounds) because the barrier drained the prefetch — guide m218's exact finding.
// B=16, C=512, HEADS=8, D=64, N=4096.
// GEMM convention: C[m][n] = sum_k A[m][k]*Bt[n][k] (both K-contiguous, mfma 16x16x32 bf16).
// LDS slab layout per buffer: A[k4][row][8] @0, B[k4][row][8] @4096 (u16 units).

typedef __bf16 bf16_t;
typedef bf16_t bf16x8 __attribute__((ext_vector_type(8)));
typedef float f32x4 __attribute__((ext_vector_type(4)));
typedef unsigned short u16;

#define VMWAIT(N) asm volatile("s_waitcnt vmcnt(" #N ")" ::: "memory")
#define SBAR()    asm volatile("s_barrier" ::: "memory")

__device__ __forceinline__ u16 f2bf(float f) {
    unsigned u = __builtin_bit_cast(unsigned, f);
    u += 0x7FFFu + ((u >> 16) & 1u);   // RNE
    return (u16)(u >> 16);
}
__device__ __forceinline__ float bf2f(u16 h) {
    return __builtin_bit_cast(float, ((unsigned)h) << 16);
}

__device__ __forceinline__ void gload_lds16(const u16* g, u16* l) {
    __builtin_amdgcn_global_load_lds((const __attribute__((address_space(1))) void*)g,
                                     (__attribute__((address_space(3))) void*)l, 16, 0, 0);
}
__device__ __forceinline__ bf16x8 ldfrag(const u16* p) {
    return *(const bf16x8*)p;
}

// ---------------- weight cast (+ Wq transpose) ----------------
__global__ __launch_bounds__(256) void cast_weights(const float* __restrict__ Wq, const float* __restrict__ Wk,
                                                    const float* __restrict__ Wv, const float* __restrict__ Wo,
                                                    u16* __restrict__ WqT, u16* __restrict__ WkB,
                                                    u16* __restrict__ WvB, u16* __restrict__ WoB) {
    int i = blockIdx.x * 256 + threadIdx.x;      // 0..262143
    WkB[i] = f2bf(Wk[i]);
    WvB[i] = f2bf(Wv[i]);
    WoB[i] = f2bf(Wo[i]);
    int o = i >> 9, c = i & 511;
    WqT[c * 512 + o] = f2bf(Wq[i]);              // WqT[c][o]
}

// ---------------- x [b][512][4096] f32 -> xT [b][4096][512] bf16 ----------------
__global__ __launch_bounds__(256) void transpose_cast(const float* __restrict__ x, u16* __restrict__ xT) {
    __shared__ u16 tile[64][65];
    int nt = blockIdx.x, ct = blockIdx.y, b = blockIdx.z;
    const float* xb = x + ((size_t)b * 512 + ct * 64) * 4096 + nt * 64;
    int t = threadIdx.x;
#pragma unroll
    for (int i = 0; i < 16; ++i) {
        int idx = i * 256 + t;
        int cl = idx >> 6, nl = idx & 63;
        tile[cl][nl] = f2bf(xb[(size_t)cl * 4096 + nl]);
    }
    __syncthreads();
    u16* xTb = xT + ((size_t)b * 4096 + nt * 64) * 512 + ct * 64;
#pragma unroll
    for (int i = 0; i < 16; ++i) {
        int idx = i * 256 + t;
        int nl = idx >> 6, cl = idx & 63;
        xTb[(size_t)nl * 512 + cl] = tile[cl][nl];
    }
}

// ---------------- 128x128x512 GEMM core: ring-of-3, counted vmcnt ----------------
// lds: 3 buffers x 8192 u16 (A@0, B@4096 within each) = 48KB.
__device__ __forceinline__ void stageAB128(const u16* __restrict__ Ab, const u16* __restrict__ Btb,
                                           u16* base, int kb, int t) {
    const int r0 = t & 127, k40 = t >> 7;        // k40 in {0,1}; +2 for second chunk
    gload_lds16(Ab + (size_t)r0 * 512 + kb + k40 * 8, base + t * 8);
    gload_lds16(Ab + (size_t)r0 * 512 + kb + (k40 + 2) * 8, base + (t + 256) * 8);
    gload_lds16(Btb + (size_t)r0 * 512 + kb + k40 * 8, base + 4096 + t * 8);
    gload_lds16(Btb + (size_t)r0 * 512 + kb + (k40 + 2) * 8, base + 4096 + (t + 256) * 8);
}

__device__ __forceinline__ void gemm128_ring(const u16* __restrict__ Ab, const u16* __restrict__ Btb,
                                             u16* lds, f32x4 acc[4][4]) {
    const int t = threadIdx.x;
    const int l = t & 63, w = t >> 6;
    const int lrow = l & 15, lk = l >> 4;
    const int wm = w >> 1, wn = w & 1;
    stageAB128(Ab, Btb, lds, 0, t);              // tile 0 -> buf0   (4 loads)
    stageAB128(Ab, Btb, lds + 8192, 32, t);      // tile 1 -> buf1   (4 loads)
#pragma unroll
    for (int kt = 0; kt < 16; ++kt) {
        u16* cur = lds + (kt % 3) * 8192;
        if (kt < 14) {
            // stage tile kt+2 into buf[(kt+2)%3] (last read at iter kt-1; barrier-protected)
            stageAB128(Ab, Btb, lds + ((kt + 2) % 3) * 8192, (kt + 2) * 32, t);
            VMWAIT(8);                           // cur's 4 done; 8 prefetch loads stay in flight
        } else if (kt == 14) {
            VMWAIT(4);
        } else {
            VMWAIT(0);
        }
        SBAR();                                  // all waves see cur staged
        bf16x8 av[4], bv[4];
#pragma unroll
        for (int fi = 0; fi < 4; ++fi)
            av[fi] = ldfrag(cur + lk * 1024 + (wm * 64 + fi * 16 + lrow) * 8);
#pragma unroll
        for (int fj = 0; fj < 4; ++fj)
            bv[fj] = ldfrag(cur + 4096 + lk * 1024 + (wn * 64 + fj * 16 + lrow) * 8);
#pragma unroll
        for (int fi = 0; fi < 4; ++fi)
#pragma unroll
            for (int fj = 0; fj < 4; ++fj)
                acc[fi][fj] = __builtin_amdgcn_mfma_f32_16x16x32_bf16(av[fi], bv[fj], acc[fi][fj], 0, 0, 0);
        SBAR();                                  // all waves done reading cur before it's restaged
    }
}

// ---------------- stacked [K;V] projection GEMM (M=1024) ----------------
__global__ __launch_bounds__(256) void kgemm_kv(const u16* __restrict__ Wkv, const u16* __restrict__ xT,
                                                u16* __restrict__ K, u16* __restrict__ V) {
    __shared__ __align__(16) u16 lds[24576];
    const int b = blockIdx.y;
    const int bm = blockIdx.x >> 5, bn = blockIdx.x & 31;
    const u16* Ab = Wkv + (size_t)bm * 128 * 512;
    const u16* Btb = xT + (size_t)b * 2097152 + (size_t)bn * 128 * 512;
    f32x4 acc[4][4];
#pragma unroll
    for (int i = 0; i < 4; ++i)
#pragma unroll
        for (int j = 0; j < 4; ++j) acc[i][j] = (f32x4){0.f, 0.f, 0.f, 0.f};
    gemm128_ring(Ab, Btb, lds, acc);
    const int t = threadIdx.x, l = t & 63, w = t >> 6;
    const int lrow = l & 15, lk = l >> 4;
    const int wm = w >> 1, wn = w & 1;
    u16* Cb = (bm < 4) ? (K + (size_t)b * 2097152 + (size_t)bm * 128 * 4096)
                       : (V + (size_t)b * 2097152 + (size_t)(bm - 4) * 128 * 4096);
#pragma unroll
    for (int fi = 0; fi < 4; ++fi)
#pragma unroll
        for (int fj = 0; fj < 4; ++fj)
#pragma unroll
            for (int r = 0; r < 4; ++r) {
                int m = wm * 64 + fi * 16 + lk * 4 + r;
                int n = bn * 128 + wn * 64 + fj * 16 + lrow;
                Cb[(size_t)m * 4096 + n] = f2bf(acc[fi][fj][r]);
            }
}

// ---------------- generic GEMM -> bf16 out (used for Wfinal) ----------------
__global__ __launch_bounds__(256) void kgemm_bf16(const u16* __restrict__ A, long long sA,
                                                  const u16* __restrict__ Bt, long long sB,
                                                  u16* __restrict__ C, long long sC, int ldc, int Nt) {
    __shared__ __align__(16) u16 lds[24576];
    const int b = blockIdx.y;
    const int bm = blockIdx.x / Nt, bn = blockIdx.x % Nt;
    const u16* Ab = A + (size_t)b * sA + (size_t)bm * 128 * 512;
    const u16* Btb = Bt + (size_t)b * sB + (size_t)bn * 128 * 512;
    f32x4 acc[4][4];
#pragma unroll
    for (int i = 0; i < 4; ++i)
#pragma unroll
        for (int j = 0; j < 4; ++j) acc[i][j] = (f32x4){0.f, 0.f, 0.f, 0.f};
    gemm128_ring(Ab, Btb, lds, acc);
    const int t = threadIdx.x, l = t & 63, w = t >> 6;
    const int lrow = l & 15, lk = l >> 4;
    const int wm = w >> 1, wn = w & 1;
    u16* Cb = C + (size_t)b * sC;
#pragma unroll
    for (int fi = 0; fi < 4; ++fi)
#pragma unroll
        for (int fj = 0; fj < 4; ++fj)
#pragma unroll
            for (int r = 0; r < 4; ++r) {
                int m = bm * 128 + wm * 64 + fi * 16 + lk * 4 + r;
                int n = bn * 128 + wn * 64 + fj * 16 + lrow;
                Cb[(size_t)m * ldc + n] = f2bf(acc[fi][fj][r]);
            }
}

// ---------------- final GEMM + residual + BN stats, bf16 y out ----------------
__global__ __launch_bounds__(256) void kgemm_f32res(const u16* __restrict__ Wfin, const u16* __restrict__ xT,
                                                    const float* __restrict__ xres, u16* __restrict__ yb,
                                                    float* __restrict__ sums, float* __restrict__ sumsq) {
    __shared__ __align__(16) u16 lds[24576];
    const int b = blockIdx.y;
    const int bm = blockIdx.x >> 5, bn = blockIdx.x & 31;
    const u16* Ab = Wfin + (size_t)b * 262144 + (size_t)bm * 128 * 512;
    const u16* Btb = xT + (size_t)b * 2097152 + (size_t)bn * 128 * 512;
    f32x4 acc[4][4];
#pragma unroll
    for (int i = 0; i < 4; ++i)
#pragma unroll
        for (int j = 0; j < 4; ++j) acc[i][j] = (f32x4){0.f, 0.f, 0.f, 0.f};
    gemm128_ring(Ab, Btb, lds, acc);
    const int t = threadIdx.x, l = t & 63, w = t >> 6;
    const int lrow = l & 15, lk = l >> 4;
    const int wm = w >> 1, wn = w & 1;
#pragma unroll
    for (int fi = 0; fi < 4; ++fi)
#pragma unroll
        for (int r = 0; r < 4; ++r) {
            int mg = bm * 128 + wm * 64 + fi * 16 + lk * 4 + r;             // channel
            size_t rowbase = (size_t)b * 2097152 + (size_t)mg * 4096 + bn * 128 + wn * 64;
            float rs = 0.f, rq = 0.f;
#pragma unroll
            for (int fj = 0; fj < 4; ++fj) {
                int nc = fj * 16 + lrow;
                float v = acc[fi][fj][r] + xres[rowbase + nc];
                yb[rowbase + nc] = f2bf(v);
                rs += v; rq += v * v;
            }
#pragma unroll
            for (int off = 1; off < 16; off <<= 1) {
                rs += __shfl_xor(rs, off);
                rq += __shfl_xor(rq, off);
            }
            if (lrow == 0) {
                atomicAdd(&sums[mg], rs);
                atomicAdd(&sumsq[mg], rq);
            }
        }
}

// ---------------- softmax over head-dim (in place on K [b][512][4096]) ----------------
__global__ __launch_bounds__(256) void softmax_k(u16* __restrict__ K) {
    int gid = blockIdx.x * 256 + threadIdx.x;    // 16*8*4096 = 524288
    int n = gid & 4095, bh = gid >> 12;
    u16* p = K + (size_t)bh * 64 * 4096 + n;
    float v[64];
    float m = -1e30f;
#pragma unroll
    for (int d = 0; d < 64; ++d) { v[d] = bf2f(p[(size_t)d * 4096]); m = fmaxf(m, v[d]); }
    float s = 0.f;
#pragma unroll
    for (int d = 0; d < 64; ++d) { v[d] = __expf(v[d] - m); s += v[d]; }
    float inv = 1.0f / s;
#pragma unroll
    for (int d = 0; d < 64; ++d) p[(size_t)d * 4096] = f2bf(v[d] * inv);
}

// ---------------- ctx partials: per (b,h,ks) 64x64 over K-range 512, ring-of-3 ----------------
__global__ __launch_bounds__(256) void ctx_partial(const u16* __restrict__ Ksm, const u16* __restrict__ V,
                                                   float* __restrict__ P) {
    __shared__ __align__(16) u16 lds[12288];     // 3 x (A 2048 + B 2048) u16
    const int bh = blockIdx.x >> 3, ks = blockIdx.x & 7;
    const u16* Ab = Ksm + (size_t)bh * 262144;
    const u16* Btb = V + (size_t)bh * 262144;
    const int t = threadIdx.x, l = t & 63, w = t >> 6;
    const int lrow = l & 15, lk = l >> 4;
    const int wm = w >> 1, wn = w & 1;
    const int row = t & 63, k4 = t >> 6;
    f32x4 acc[2][2];
#pragma unroll
    for (int i = 0; i < 2; ++i)
#pragma unroll
        for (int j = 0; j < 2; ++j) acc[i][j] = (f32x4){0.f, 0.f, 0.f, 0.f};
    const size_t rA = (size_t)row * 4096 + ks * 512 + k4 * 8;
    gload_lds16(Ab + rA, lds + t * 8);
    gload_lds16(Btb + rA, lds + 2048 + t * 8);
    gload_lds16(Ab + rA + 32, lds + 4096 + t * 8);
    gload_lds16(Btb + rA + 32, lds + 6144 + t * 8);
#pragma unroll
    for (int kt = 0; kt < 16; ++kt) {
        u16* cur = lds + (kt % 3) * 4096;
        if (kt < 14) {
            u16* nb = lds + ((kt + 2) % 3) * 4096;
            gload_lds16(Ab + rA + (kt + 2) * 32, nb + t * 8);
            gload_lds16(Btb + rA + (kt + 2) * 32, nb + 2048 + t * 8);
            VMWAIT(4);
        } else if (kt == 14) {
            VMWAIT(2);
        } else {
            VMWAIT(0);
        }
        SBAR();
        bf16x8 av[2], bv[2];
#pragma unroll
        for (int fi = 0; fi < 2; ++fi)
            av[fi] = ldfrag(cur + lk * 512 + (wm * 32 + fi * 16 + lrow) * 8);
#pragma unroll
        for (int fj = 0; fj < 2; ++fj)
            bv[fj] = ldfrag(cur + 2048 + lk * 512 + (wn * 32 + fj * 16 + lrow) * 8);
#pragma unroll
        for (int fi = 0; fi < 2; ++fi)
#pragma unroll
            for (int fj = 0; fj < 2; ++fj)
                acc[fi][fj] = __builtin_amdgcn_mfma_f32_16x16x32_bf16(av[fi], bv[fj], acc[fi][fj], 0, 0, 0);
        SBAR();
    }
    float* Pb = P + (size_t)blockIdx.x * 4096;
#pragma unroll
    for (int fi = 0; fi < 2; ++fi)
#pragma unroll
        for (int fj = 0; fj < 2; ++fj)
#pragma unroll
            for (int r = 0; r < 4; ++r) {
                int m = wm * 32 + fi * 16 + lk * 4 + r;
                int e = wn * 32 + fj * 16 + lrow;
                Pb[m * 64 + e] = acc[fi][fj][r];
            }
}

// ---------------- reduce 8 partials -> ctxT[bh][e][d] bf16 ----------------
__global__ __launch_bounds__(256) void ctx_reduce(const float* __restrict__ P, u16* __restrict__ ctxT) {
    int gid = blockIdx.x * 256 + threadIdx.x;    // 524288
    int d = gid & 63, e = (gid >> 6) & 63, bh = gid >> 12;
    const float* p = P + (size_t)bh * 8 * 4096 + d * 64 + e;
    float s = 0.f;
#pragma unroll
    for (int ks = 0; ks < 8; ++ks) s += p[(size_t)ks * 4096];
    ctxT[(size_t)bh * 4096 + e * 64 + d] = f2bf(s);
}

// ---------------- Wq'^T[b][c][h*64+e] = sum_d ctxT[bh][e][d] * WqT[c][h*64+d] ----------------
__global__ __launch_bounds__(256) void kgemm_wqp(const u16* __restrict__ ctxT, const u16* __restrict__ WqT,
                                                 u16* __restrict__ WqpT) {
    __shared__ __align__(16) u16 lds[4096 + 8192];
    const int nq = blockIdx.x, bh = blockIdx.y;
    const int b = bh >> 3, h = bh & 7;
    const u16* Ab = ctxT + (size_t)bh * 4096;                       // [e][d] lda=64
    const u16* Btb = WqT + (size_t)nq * 128 * 512 + h * 64;         // rows c, ldb=512
    u16* Asl = lds; u16* Bsl = lds + 4096;
    const int t = threadIdx.x, l = t & 63, w = t >> 6;
    const int lrow = l & 15, lk = l >> 4;
    {
        int q = t;
        gload_lds16(Ab + (size_t)(q & 63) * 64 + (q >> 6) * 8, Asl + q * 8);
        q = t + 256;
        gload_lds16(Ab + (size_t)(q & 63) * 64 + (q >> 6) * 8, Asl + q * 8);
    }
#pragma unroll
    for (int i = 0; i < 4; ++i) {
        int q = t + i * 256;
        gload_lds16(Btb + (size_t)(q & 127) * 512 + (q >> 7) * 8, Bsl + q * 8);
    }
    __syncthreads();
    f32x4 acc[4][2];
#pragma unroll
    for (int i = 0; i < 4; ++i)
#pragma unroll
        for (int j = 0; j < 2; ++j) acc[i][j] = (f32x4){0.f, 0.f, 0.f, 0.f};
#pragma unroll
    for (int ksv = 0; ksv < 2; ++ksv) {
        bf16x8 av[4], bv[2];
#pragma unroll
        for (int fi = 0; fi < 4; ++fi)
            av[fi] = ldfrag(Asl + (ksv * 4 + lk) * 512 + (fi * 16 + lrow) * 8);
#pragma unroll
        for (int fj = 0; fj < 2; ++fj)
            bv[fj] = ldfrag(Bsl + (ksv * 4 + lk) * 1024 + (w * 32 + fj * 16 + lrow) * 8);
#pragma unroll
        for (int fi = 0; fi < 4; ++fi)
#pragma unroll
            for (int fj = 0; fj < 2; ++fj)
                acc[fi][fj] = __builtin_amdgcn_mfma_f32_16x16x32_bf16(av[fi], bv[fj], acc[fi][fj], 0, 0, 0);
    }
    u16* Ob = WqpT + (size_t)b * 262144 + h * 64;
#pragma unroll
    for (int fi = 0; fi < 4; ++fi)
#pragma unroll
        for (int fj = 0; fj < 2; ++fj)
#pragma unroll
            for (int r = 0; r < 4; ++r) {
                int e = fi * 16 + lk * 4 + r;
                int c = nq * 128 + w * 32 + fj * 16 + lrow;
                Ob[(size_t)c * 512 + e] = f2bf(acc[fi][fj][r]);
            }
}

// ---------------- BN finalize + normalize (bf16 y -> f32 out) ----------------
__global__ void bn_finalize(const float* __restrict__ sums, const float* __restrict__ sumsq,
                            const float* __restrict__ gamma, const float* __restrict__ beta,
                            float* __restrict__ scale, float* __restrict__ shift) {
    int c = threadIdx.x;                 // block of 512
    float inv = 1.0f / 65536.0f;
    float mean = sums[c] * inv;
    float var = sumsq[c] * inv - mean * mean;
    float rstd = rsqrtf(var + 1e-5f);
    float sc = rstd * gamma[c];
    scale[c] = sc;
    shift[c] = beta[c] - mean * sc;
}

__global__ __launch_bounds__(256) void bn_norm(const u16* __restrict__ yb, const float* __restrict__ scale,
                                               const float* __restrict__ shift, float* __restrict__ out) {
    int i8 = blockIdx.x * 256 + threadIdx.x;     // 4194304 groups of 8 bf16
    uint4 raw = ((const uint4*)yb)[i8];
    int c = (i8 >> 9) & 511;                     // 8 elems/thread, 4096 n per c
    float sc = scale[c], sh = shift[c];
    float4 o0, o1;
    o0.x = bf2f((u16)(raw.x & 0xffff)) * sc + sh;  o0.y = bf2f((u16)(raw.x >> 16)) * sc + sh;
    o0.z = bf2f((u16)(raw.y & 0xffff)) * sc + sh;  o0.w = bf2f((u16)(raw.y >> 16)) * sc + sh;
    o1.x = bf2f((u16)(raw.z & 0xffff)) * sc + sh;  o1.y = bf2f((u16)(raw.z >> 16)) * sc + sh;
    o1.z = bf2f((u16)(raw.w & 0xffff)) * sc + sh;  o1.w = bf2f((u16)(raw.w >> 16)) * sc + sh;
    float4* O = (float4*)out;
    O[(size_t)i8 * 2] = o0;
    O[(size_t)i8 * 2 + 1] = o1;
}

extern "C" void kernel_launch(void* const* d_in, const int* in_sizes, int n_in,
                              void* d_out, int out_size, void* d_ws, size_t ws_size,
                              hipStream_t stream) {
    const float* x     = (const float*)d_in[0];
    const float* Wq    = (const float*)d_in[1];
    const float* Wk    = (const float*)d_in[2];
    const float* Wv    = (const float*)d_in[3];
    const float* Wo    = (const float*)d_in[4];
    const float* gamma = (const float*)d_in[5];
    const float* beta  = (const float*)d_in[6];

    // ---- d_ws layout (~138 MiB): xT | Kbuf(->ybuf) | weights | Wfin | stats ----
    char* w = (char*)d_ws;
    u16* xT   = (u16*)(w);                                     //  64 MiB
    u16* Kbuf = (u16*)(w + 67108864ull);                       //  64 MiB (reused as ybuf after ctx)
    u16* WqT  = (u16*)(w + 134217728ull);                      // 512 KiB
    u16* WkB  = WqT + 262144;                                  // [Wk;Wv] stacked (adjacent!)
    u16* WvB  = WkB + 262144;
    u16* WoB  = WvB + 262144;
    u16* Wfin = WoB + 262144;                                  // 8 MiB
    float* sums  = (float*)(w + 134217728ull + 2097152ull + 8388608ull);
    float* sumsq = sums + 512;
    float* scale = sums + 1024;
    float* shift = sums + 1536;
    u16* ybuf = Kbuf;                                          // Kbuf dead after ctx_partial

    // ---- d_out doubles as scratch (all dead before bn_norm overwrites d_out) ----
    char* ob = (char*)d_out;
    float* ctxP = (float*)ob;                                  // 16 MiB  @0
    u16* Vbuf   = (u16*)(ob + 16777216ull);                    // 64 MiB  @16M
    u16* ctxT   = (u16*)(ob + 83886080ull);                    //  1 MiB  @80M
    u16* WqpT   = (u16*)(ob + 84934656ull);                    //  8 MiB  @81M
    float* out  = (float*)d_out;

    hipMemsetAsync(sums, 0, 4096, stream);
    cast_weights<<<1024, 256, 0, stream>>>(Wq, Wk, Wv, Wo, WqT, WkB, WvB, WoB);
    transpose_cast<<<dim3(64, 8, 16), 256, 0, stream>>>(x, xT);
    kgemm_kv<<<dim3(256, 16), 256, 0, stream>>>(WkB, xT, Kbuf, Vbuf);
    softmax_k<<<2048, 256, 0, stream>>>(Kbuf);
    ctx_partial<<<1024, 256, 0, stream>>>(Kbuf, Vbuf, ctxP);
    ctx_reduce<<<2048, 256, 0, stream>>>(ctxP, ctxT);
    kgemm_wqp<<<dim3(4, 128), 256, 0, stream>>>(ctxT, WqT, WqpT);
    kgemm_bf16<<<dim3(16, 16), 256, 0, stream>>>(WoB, 0, WqpT, 262144, Wfin, 262144, 512, 4);
    kgemm_f32res<<<dim3(128, 16), 256, 0, stream>>>(Wfin, xT, x, ybuf, sums, sumsq);
    bn_finalize<<<1, 512, 0, stream>>>(sums, sumsq, gamma, beta, scale, shift);
    bn_norm<<<16384, 256, 0, stream>>>(ybuf, scale, shift, out);
}